// Round 15
// baseline (11093.929 us; speedup 1.0000x reference)
//
#include <hip/hip_runtime.h>
#include <hip/hip_fp16.h>
#include <cstdint>
#include <cstddef>

// Sizes: B=64, T=1024, I=64, H=256, G=3H=768, N=B*T=65536

typedef _Float16 f16x8 __attribute__((ext_vector_type(8)));
typedef float f32x4 __attribute__((ext_vector_type(4)));

// Pinned v_dot2_f32_f16 (used by gemm_xw2)
#define DOT2(acc, w, h) \
    asm("v_dot2_f32_f16 %0, %1, %2, %0" : "+v"(acc) : "v"(w), "v"(h))

// Pin weight words into AGPRs ("a" class): loads hoist once, MFMA reads
// AGPR operands natively, arch-VGPR budget stays free for the working set.
#define PINA(x) asm volatile("" : "+a"(x))
#define PINA4(q) do { PINA(q.x); PINA(q.y); PINA(q.z); PINA(q.w); } while (0)

// LDS-only barrier: do NOT drain vmcnt (global loads/stores stay in flight).
__device__ __forceinline__ void lds_barrier() {
    asm volatile("s_waitcnt lgkmcnt(0)\n\ts_barrier" ::: "memory");
}

// Fast transcendentals: raw v_exp (2^x) + v_rcp.
__device__ __forceinline__ float fast_sigmoid(float x) {
    float t = x * -1.4426950408889634f, e, r;
    asm("v_exp_f32 %0, %1" : "=v"(e) : "v"(t));
    float d = 1.f + e;
    asm("v_rcp_f32 %0, %1" : "=v"(r) : "v"(d));
    return r;
}
__device__ __forceinline__ float fast_tanh_clamped(float x) {  // |x| <= 15
    float t = x * 2.8853900817779268f, e, r;                   // 2*log2(e)
    asm("v_exp_f32 %0, %1" : "=v"(e) : "v"(t));
    float d = e + 1.f;
    asm("v_rcp_f32 %0, %1" : "=v"(r) : "v"(d));
    return 1.f - 2.f * r;
}

// Pack w_hh [768][256] f32 -> f16 row-major [768][256]
__global__ void pack_whh(const float* __restrict__ w1, const float* __restrict__ w2,
                         __half2* __restrict__ o1, __half2* __restrict__ o2) {
    int g = blockIdx.x;
    int k2 = threadIdx.x;
    const float* w = blockIdx.y ? w2 : w1;
    __half2* o = blockIdx.y ? o2 : o1;
    float a = w[g * 256 + 2 * k2];
    float b = w[g * 256 + 2 * k2 + 1];
    o[g * 128 + k2] = __floats2half2_rn(a, b);
}

// xw1 = x[65536,64] @ w_ih1[768,64]^T + b_ih1 -> f16 [65536,768]
__global__ __launch_bounds__(256)
void gemm_xw1(const float* __restrict__ A, const float* __restrict__ W,
              const float* __restrict__ bias, __half* __restrict__ out) {
    __shared__ float As[64][65];
    __shared__ float Ws[64][65];
    const int tid = threadIdx.x;
    const int n0 = blockIdx.y * 64, g0 = blockIdx.x * 64;
    for (int idx = tid; idx < 4096; idx += 256) {
        int r = idx >> 6, c = idx & 63;
        As[r][c] = A[(size_t)(n0 + r) * 64 + c];
        Ws[r][c] = W[(size_t)(g0 + r) * 64 + c];
    }
    __syncthreads();
    const int ty = tid >> 4, tx = tid & 15;
    float acc[4][4] = {};
    for (int k = 0; k < 64; ++k) {
        float a[4], w[4];
        #pragma unroll
        for (int i = 0; i < 4; ++i) a[i] = As[ty * 4 + i][k];
        #pragma unroll
        for (int jj = 0; jj < 4; ++jj) w[jj] = Ws[tx * 4 + jj][k];
        #pragma unroll
        for (int i = 0; i < 4; ++i)
            #pragma unroll
            for (int jj = 0; jj < 4; ++jj) acc[i][jj] += a[i] * w[jj];
    }
    #pragma unroll
    for (int jj = 0; jj < 4; ++jj) {
        float bb = bias[g0 + tx * 4 + jj];
        #pragma unroll
        for (int i = 0; i < 4; ++i)
            out[(size_t)(n0 + ty * 4 + i) * 768 + (g0 + tx * 4 + jj)] =
                __float2half(acc[i][jj] + bb);
    }
}

// xw2 = y1[65536,256](f16) @ w_eff[768,256](f16)^T + b_eff -> f16 [65536,768]
__global__ __launch_bounds__(256)
void gemm_xw2(const __half2* __restrict__ A, const __half2* __restrict__ W,
              const float* __restrict__ bias, __half* __restrict__ out) {
    __shared__ __half2 As[64][33];
    __shared__ __half2 Ws[64][33];
    const int tid = threadIdx.x;
    const int n0 = blockIdx.y * 64, g0 = blockIdx.x * 64;
    const int ty = tid >> 4, tx = tid & 15;
    float acc[4][4] = {};
    for (int kc = 0; kc < 4; ++kc) {
        __syncthreads();
        for (int idx = tid; idx < 2048; idx += 256) {
            int r = idx >> 5, c2 = idx & 31;
            As[r][c2] = A[(size_t)(n0 + r) * 128 + kc * 32 + c2];
            Ws[r][c2] = W[(size_t)(g0 + r) * 128 + kc * 32 + c2];
        }
        __syncthreads();
        #pragma unroll 8
        for (int k2 = 0; k2 < 32; ++k2) {
            unsigned int a2[4], w2[4];
            #pragma unroll
            for (int i = 0; i < 4; ++i)
                a2[i] = __builtin_bit_cast(unsigned int, As[ty * 4 + i][k2]);
            #pragma unroll
            for (int jj = 0; jj < 4; ++jj)
                w2[jj] = __builtin_bit_cast(unsigned int, Ws[tx * 4 + jj][k2]);
            #pragma unroll
            for (int i = 0; i < 4; ++i)
                #pragma unroll
                for (int jj = 0; jj < 4; ++jj)
                    DOT2(acc[i][jj], w2[jj], a2[i]);
        }
    }
    #pragma unroll
    for (int jj = 0; jj < 4; ++jj) {
        float bb = bias[g0 + tx * 4 + jj];
        #pragma unroll
        for (int i = 0; i < 4; ++i)
            out[(size_t)(n0 + ty * 4 + i) * 768 + (g0 + tx * 4 + jj)] =
                __float2half(acc[i][jj] + bb);
    }
}

// GRU recurrence, full-M MFMA: 4 blocks x 16 batches; 512 threads = 8 waves.
// A = h[16 batches][256 units] shared by all waves, fragment-ordered in LDS
// ([kt][lane][8]: conflict-free ds_read_b128 at the 1KB/wave floor).
// Wave w owns units [w*32,(w+1)*32): 48 B-fragments (192 AGPRs, loaded once).
// Per step/wave: 8 ds_read_b128 + 48 MFMA (6 interleaved chains, kt-outer) +
// fully lane-parallel nonlinearity (each lane: 4 batches x 2 units).
// Layouts (validated in round 14, M=1): A[lm][kt*32+lk*8+j], B[row u][k] 16B
// contiguous, D reg i = (batch lk*4+i, unit lm).
__global__ __launch_bounds__(512, 2)
void rec_kernel(const __half* __restrict__ wpack,  // [768][256] f16 row-major
                const float* __restrict__ b_hh,    // [768]
                const __half* __restrict__ xw,     // [64][1024][768]
                __half* __restrict__ y) {          // [64][1024][256]
    __shared__ __align__(16) __half afrag[2][8][64][8];  // 16KB
    const int tid = threadIdx.x;
    const int w = tid >> 6, l = tid & 63;
    const int lm = l & 15, lk = l >> 4;
    const int bk = blockIdx.x;   // 0..3
    const int wb = w * 32;

    // B-fragments: [sel][gate][kt]; row = g*256 + wb + sel*16 + lm
    uint4 Bf[2][3][8];
    {
        const char* wb8 = (const char*)wpack;
        #pragma unroll
        for (int sel = 0; sel < 2; ++sel)
            #pragma unroll
            for (int g = 0; g < 3; ++g)
                #pragma unroll
                for (int kt = 0; kt < 8; ++kt) {
                    int gr = g * 256 + wb + sel * 16 + lm;
                    Bf[sel][g][kt] =
                        *(const uint4*)(wb8 + (size_t)gr * 512 + kt * 64 + lk * 16);
                    PINA4(Bf[sel][g][kt]);
                }
    }

    float bb[2][3];
    #pragma unroll
    for (int sel = 0; sel < 2; ++sel)
        #pragma unroll
        for (int g = 0; g < 3; ++g)
            bb[sel][g] = b_hh[g * 256 + wb + sel * 16 + lm];

    // zero both A buffers (h0 = 0)
    for (int idx = tid; idx < 1024; idx += 512)
        ((uint4*)afrag)[idx] = uint4{0u, 0u, 0u, 0u};

    // per-lane batch pointers (4 batches lk*4+i)
    const __half* xb[4];
    __half* yb[4];
    #pragma unroll
    for (int i = 0; i < 4; ++i) {
        int gbatch = bk * 16 + lk * 4 + i;
        xb[i] = xw + (size_t)gbatch * 1024 * 768;
        yb[i] = y + (size_t)gbatch * 1024 * 256;
    }

    float hp[2][4] = {};
    // prefetch t=0 xw
    __half nx[2][3][4];
    #pragma unroll
    for (int sel = 0; sel < 2; ++sel)
        #pragma unroll
        for (int g = 0; g < 3; ++g)
            #pragma unroll
            for (int i = 0; i < 4; ++i)
                nx[sel][g][i] = xb[i][g * 256 + wb + sel * 16 + lm];
    __syncthreads();

    for (int t = 0; t < 1024; ++t) {
        __half cx[2][3][4];
        #pragma unroll
        for (int sel = 0; sel < 2; ++sel)
            #pragma unroll
            for (int g = 0; g < 3; ++g)
                #pragma unroll
                for (int i = 0; i < 4; ++i)
                    cx[sel][g][i] = nx[sel][g][i];
        // issue t+1 loads (t=1023 over-read lands in the adjacent y1 region)
        {
            const size_t o = (size_t)(t + 1) * 768;
            #pragma unroll
            for (int sel = 0; sel < 2; ++sel)
                #pragma unroll
                for (int g = 0; g < 3; ++g)
                    #pragma unroll
                    for (int i = 0; i < 4; ++i)
                        nx[sel][g][i] = xb[i][o + g * 256 + wb + sel * 16 + lm];
        }

        // A-fragments (shared by all 6 chains): conflict-free reads
        const __half* ab = &afrag[t & 1][0][0][0];
        f16x8 a[8];
        #pragma unroll
        for (int kt = 0; kt < 8; ++kt)
            a[kt] = *(const f16x8*)(ab + kt * 512 + l * 8);

        f32x4 acc[2][3];
        #pragma unroll
        for (int sel = 0; sel < 2; ++sel)
            #pragma unroll
            for (int g = 0; g < 3; ++g)
                acc[sel][g] = f32x4{0.f, 0.f, 0.f, 0.f};
        #pragma unroll
        for (int kt = 0; kt < 8; ++kt)
            #pragma unroll
            for (int sel = 0; sel < 2; ++sel)
                #pragma unroll
                for (int g = 0; g < 3; ++g)
                    acc[sel][g] = __builtin_amdgcn_mfma_f32_16x16x32_f16(
                        a[kt], __builtin_bit_cast(f16x8, Bf[sel][g][kt]),
                        acc[sel][g], 0, 0, 0);

        // nonlinearity: lane handles 4 batches x 2 units — all 64 lanes active
        __half* nbuf = &afrag[(t + 1) & 1][0][0][0];
        #pragma unroll
        for (int sel = 0; sel < 2; ++sel) {
            const int u = wb + sel * 16 + lm;
            __half* aw = nbuf + (u >> 5) * 512 + ((u >> 3) & 3) * 128 + (u & 7);
            #pragma unroll
            for (int i = 0; i < 4; ++i) {
                float xr = __half2float(cx[sel][0][i]);
                float xz = __half2float(cx[sel][1][i]);
                float xn = __half2float(cx[sel][2][i]);
                float hr = acc[sel][0][i] + bb[sel][0];
                float hz = acc[sel][1][i] + bb[sel][1];
                float hn = acc[sel][2][i] + bb[sel][2];
                float r = fast_sigmoid(xr + hr);
                float z = fast_sigmoid(xz + hz);
                float pa = xn + r * hn;
                pa = fminf(fmaxf(pa, -15.f), 15.f);
                float nn = fast_tanh_clamped(pa);
                float h = (1.f - z) * nn + z * hp[sel][i];
                hp[sel][i] = h;
                __half yh = __float2half(h);
                aw[(lk * 4 + i) * 8] = yh;                // frag-ordered h write
                yb[i][(size_t)t * 256 + u] = yh;          // stays in flight
            }
        }
        lds_barrier();   // LDS-only drain: xw loads / y stores not drained
    }
}

// Column stats (sum, sumsq) over [65536][256] f16 -> stats[c], stats[256+c]
__global__ __launch_bounds__(256)
void bnstat(const __half* __restrict__ y, float* __restrict__ stats) {
    const int c = threadIdx.x;
    const size_t r0 = (size_t)blockIdx.x * 256;   // grid 256
    float s = 0.f, q = 0.f;
    for (int r = 0; r < 256; ++r) {
        float v = __half2float(y[(r0 + r) * 256 + c]);
        s += v; q += v * v;
    }
    atomicAdd(&stats[c], s);
    atomicAdd(&stats[256 + c], q);
}

// Layer-2: stats + per-(b,u) max/min over time
__global__ __launch_bounds__(256)
void bn2max(const __half* __restrict__ y, float* __restrict__ stats,
            float* __restrict__ mx_out, float* __restrict__ mn_out) {
    const int c = threadIdx.x, b = blockIdx.x;    // grid 64
    const __half* p = y + (size_t)b * 1024 * 256 + c;
    float s = 0.f, q = 0.f, M = -3e38f, m = 3e38f;
    for (int t = 0; t < 1024; ++t) {
        float v = __half2float(p[(size_t)t * 256]);
        s += v; q += v * v;
        M = fmaxf(M, v); m = fminf(m, v);
    }
    mx_out[b * 256 + c] = M;
    mn_out[b * 256 + c] = m;
    atomicAdd(&stats[c], s);
    atomicAdd(&stats[256 + c], q);
}

// Fold BN1 (training-mode batch stats) into layer-2 input weights.
__global__ void fold_bn1(const float* __restrict__ w_ih2, const float* __restrict__ b_ih2,
                         const float* __restrict__ g1, const float* __restrict__ be1,
                         const float* __restrict__ stats1,
                         __half* __restrict__ w_eff, float* __restrict__ b_eff) {
    const int g = blockIdx.x, lane = threadIdx.x;  // 768 blocks x 64 threads
    const float invN = 1.f / 65536.f;
    float partial = 0.f;
    for (int c = lane; c < 256; c += 64) {
        float mu = stats1[c] * invN;
        float var = stats1[256 + c] * invN - mu * mu;
        float s = g1[c] * rsqrtf(var + 1e-5f);
        float sh = be1[c] - mu * s;
        float w = w_ih2[g * 256 + c];
        w_eff[g * 256 + c] = __float2half(w * s);
        partial += w * sh;
    }
    #pragma unroll
    for (int off = 32; off > 0; off >>= 1) partial += __shfl_down(partial, off);
    if (lane == 0) b_eff[g] = b_ih2[g] + partial;
}

// BN2 affine -> time max-pool (max if scale>=0 else min) -> tanh -> FC
__global__ void final_kernel(const float* __restrict__ stats2,
                             const float* __restrict__ mx, const float* __restrict__ mn,
                             const float* __restrict__ g2, const float* __restrict__ be2,
                             const float* __restrict__ w_fc, const float* __restrict__ b_fc,
                             float* __restrict__ out) {
    __shared__ float v[256];
    const int b = blockIdx.x, c = threadIdx.x;
    const float invN = 1.f / 65536.f;
    float mu = stats2[c] * invN;
    float var = stats2[256 + c] * invN - mu * mu;
    float s = g2[c] * rsqrtf(var + 1e-5f);
    float d = be2[c] - mu * s;
    float M = (s >= 0.f) ? mx[b * 256 + c] : mn[b * 256 + c];
    v[c] = tanhf(s * M + d);
    __syncthreads();
    if (c < 128) {
        float acc = b_fc[c];
        for (int k = 0; k < 256; ++k) acc += v[k] * w_fc[c * 256 + k];
        out[b * 128 + c] = acc;
    }
}

extern "C" void kernel_launch(void* const* d_in, const int* in_sizes, int n_in,
                              void* d_out, int out_size, void* d_ws, size_t ws_size,
                              hipStream_t stream) {
    const float* x     = (const float*)d_in[0];
    const float* w_ih1 = (const float*)d_in[1];
    const float* w_hh1 = (const float*)d_in[2];
    const float* b_ih1 = (const float*)d_in[3];
    const float* b_hh1 = (const float*)d_in[4];
    const float* g1    = (const float*)d_in[5];
    const float* be1   = (const float*)d_in[6];
    const float* w_ih2 = (const float*)d_in[7];
    const float* w_hh2 = (const float*)d_in[8];
    const float* b_ih2 = (const float*)d_in[9];
    const float* b_hh2 = (const float*)d_in[10];
    const float* g2    = (const float*)d_in[11];
    const float* be2   = (const float*)d_in[12];
    const float* w_fc  = (const float*)d_in[13];
    const float* b_fc  = (const float*)d_in[14];
    float* out = (float*)d_out;

    char* ws = (char*)d_ws;
    size_t off = 0;
    __half*  xw   = (__half*)(ws + off);  off += (size_t)65536 * 768 * 2;  // shared by both layers
    __half*  y1   = (__half*)(ws + off);  off += (size_t)65536 * 256 * 2;  // layer1 out, reused for layer2 out
    __half2* wp1  = (__half2*)(ws + off); off += (size_t)768 * 128 * 4;
    __half2* wp2  = (__half2*)(ws + off); off += (size_t)768 * 128 * 4;
    __half*  weff = (__half*)(ws + off);  off += (size_t)768 * 256 * 2;
    float*   beff = (float*)(ws + off);   off += (size_t)768 * 4;
    float*   stats= (float*)(ws + off);   off += (size_t)1024 * 4;         // sum1,sq1,sum2,sq2
    float*   mx2  = (float*)(ws + off);   off += (size_t)64 * 256 * 4;
    float*   mn2  = (float*)(ws + off);   off += (size_t)64 * 256 * 4;

    (void)hipMemsetAsync(stats, 0, 4096, stream);

    pack_whh<<<dim3(768, 2), dim3(128), 0, stream>>>(w_hh1, w_hh2, wp1, wp2);
    gemm_xw1<<<dim3(12, 1024), dim3(256), 0, stream>>>(x, w_ih1, b_ih1, xw);
    rec_kernel<<<dim3(4), dim3(512), 0, stream>>>((const __half*)wp1, b_hh1, xw, y1);
    bnstat<<<dim3(256), dim3(256), 0, stream>>>(y1, stats);
    fold_bn1<<<dim3(768), dim3(64), 0, stream>>>(w_ih2, b_ih2, g1, be1, stats, weff, beff);
    gemm_xw2<<<dim3(12, 1024), dim3(256), 0, stream>>>((const __half2*)y1, (const __half2*)weff,
                                                       beff, xw);
    rec_kernel<<<dim3(4), dim3(512), 0, stream>>>((const __half*)wp2, b_hh2, xw, y1);
    bn2max<<<dim3(64), dim3(256), 0, stream>>>(y1, stats + 512, mx2, mn2);
    final_kernel<<<dim3(64), dim3(256), 0, stream>>>(stats + 512, mx2, mn2, g2, be2,
                                                     w_fc, b_fc, out);
}

// Round 17
// 9657.147 us; speedup vs baseline: 1.1488x; 1.1488x over previous
//
#include <hip/hip_runtime.h>
#include <hip/hip_fp16.h>
#include <cstdint>
#include <cstddef>

// Sizes: B=64, T=1024, I=64, H=256, G=3H=768, N=B*T=65536
// xw buffer layout (TRANSPOSED for rec): [4 bk][1024 t][768 gu][16 bi] f16,
// bi = batch&15, bk = batch>>4.

typedef _Float16 f16x8 __attribute__((ext_vector_type(8)));
typedef float f32x4 __attribute__((ext_vector_type(4)));

#define DOT2(acc, w, h) \
    asm("v_dot2_f32_f16 %0, %1, %2, %0" : "+v"(acc) : "v"(w), "v"(h))

// Pin weight words into AGPRs: loads hoist once, MFMA reads AGPRs natively.
#define PINA(x) asm volatile("" : "+a"(x))
#define PINA4(q) do { PINA(q.x); PINA(q.y); PINA(q.z); PINA(q.w); } while (0)

// LDS-only barrier: do NOT drain vmcnt (global loads/stores stay in flight).
__device__ __forceinline__ void lds_barrier() {
    asm volatile("s_waitcnt lgkmcnt(0)\n\ts_barrier" ::: "memory");
}

__device__ __forceinline__ float fast_sigmoid(float x) {
    float t = x * -1.4426950408889634f, e, r;
    asm("v_exp_f32 %0, %1" : "=v"(e) : "v"(t));
    float d = 1.f + e;
    asm("v_rcp_f32 %0, %1" : "=v"(r) : "v"(d));
    return r;
}
__device__ __forceinline__ float fast_tanh_clamped(float x) {  // |x| <= 15
    float t = x * 2.8853900817779268f, e, r;
    asm("v_exp_f32 %0, %1" : "=v"(e) : "v"(t));
    float d = e + 1.f;
    asm("v_rcp_f32 %0, %1" : "=v"(r) : "v"(d));
    return 1.f - 2.f * r;
}

// Pack w_hh [768][256] f32 -> f16 row-major [768][256]
__global__ void pack_whh(const float* __restrict__ w1, const float* __restrict__ w2,
                         __half2* __restrict__ o1, __half2* __restrict__ o2) {
    int g = blockIdx.x;
    int k2 = threadIdx.x;
    const float* w = blockIdx.y ? w2 : w1;
    __half2* o = blockIdx.y ? o2 : o1;
    float a = w[g * 256 + 2 * k2];
    float b = w[g * 256 + 2 * k2 + 1];
    o[g * 128 + k2] = __floats2half2_rn(a, b);
}

// xw1: x[65536,64] @ w_ih1[768,64]^T + b -> TRANSPOSED xwt layout.
// Block tile: n-set {16 batches (bk) x 4 t} x 64 gu. Epilogue stages C in LDS
// and writes 2KB-contiguous chunks of [t][gu][bi].
__global__ __launch_bounds__(256)
void gemm_xw1(const float* __restrict__ A, const float* __restrict__ W,
              const float* __restrict__ bias, __half* __restrict__ out) {
    __shared__ float As[64][65];
    __shared__ float Ws[64][65];
    __shared__ __align__(16) __half Cs[4][64][16];
    const int tid = threadIdx.x;
    const int g0 = blockIdx.x * 64;
    const int bk = blockIdx.y >> 8, tt = blockIdx.y & 255;
    for (int idx = tid; idx < 4096; idx += 256) {
        int r = idx >> 6, c = idx & 63;
        int n = (bk * 16 + (r & 15)) * 1024 + tt * 4 + (r >> 4);
        As[r][c] = A[(size_t)n * 64 + c];
        Ws[r][c] = W[(size_t)(g0 + r) * 64 + c];
    }
    __syncthreads();
    const int ty = tid >> 4, tx = tid & 15;
    float acc[4][4] = {};
    for (int k = 0; k < 64; ++k) {
        float a[4], w[4];
        #pragma unroll
        for (int i = 0; i < 4; ++i) a[i] = As[ty * 4 + i][k];
        #pragma unroll
        for (int jj = 0; jj < 4; ++jj) w[jj] = Ws[tx * 4 + jj][k];
        #pragma unroll
        for (int i = 0; i < 4; ++i)
            #pragma unroll
            for (int jj = 0; jj < 4; ++jj) acc[i][jj] += a[i] * w[jj];
    }
    #pragma unroll
    for (int jj = 0; jj < 4; ++jj) {
        float bb = bias[g0 + tx * 4 + jj];
        #pragma unroll
        for (int i = 0; i < 4; ++i) {
            int r = ty * 4 + i;
            Cs[r >> 4][tx * 4 + jj][r & 15] = __float2half(acc[i][jj] + bb);
        }
    }
    __syncthreads();
    // write 4 x (64 gu x 16 bi) = 4 x 2KB contiguous
    for (int q = tid; q < 512; q += 256) {
        int dt = q >> 7, w128 = q & 127;
        uint4 v = ((const uint4*)&Cs[dt][0][0])[w128];
        __half* dst = out + (((size_t)bk * 1024 + tt * 4 + dt) * 768 + g0) * 16;
        ((uint4*)dst)[w128] = v;
    }
}

// xw2: y1[65536,256](f16) @ w_eff[768,256]^T + b_eff -> TRANSPOSED xwt layout.
__global__ __launch_bounds__(256)
void gemm_xw2(const __half2* __restrict__ A, const __half2* __restrict__ W,
              const float* __restrict__ bias, __half* __restrict__ out) {
    __shared__ __half2 As[64][33];
    __shared__ __half2 Ws[64][33];
    __shared__ __align__(16) __half Cs[4][64][16];
    const int tid = threadIdx.x;
    const int g0 = blockIdx.x * 64;
    const int bk = blockIdx.y >> 8, tt = blockIdx.y & 255;
    const int ty = tid >> 4, tx = tid & 15;
    float acc[4][4] = {};
    for (int kc = 0; kc < 4; ++kc) {
        __syncthreads();
        for (int idx = tid; idx < 2048; idx += 256) {
            int r = idx >> 5, c2 = idx & 31;
            int n = (bk * 16 + (r & 15)) * 1024 + tt * 4 + (r >> 4);
            As[r][c2] = A[(size_t)n * 128 + kc * 32 + c2];
            Ws[r][c2] = W[(size_t)(g0 + r) * 128 + kc * 32 + c2];
        }
        __syncthreads();
        #pragma unroll 8
        for (int k2 = 0; k2 < 32; ++k2) {
            unsigned int a2[4], w2[4];
            #pragma unroll
            for (int i = 0; i < 4; ++i)
                a2[i] = __builtin_bit_cast(unsigned int, As[ty * 4 + i][k2]);
            #pragma unroll
            for (int jj = 0; jj < 4; ++jj)
                w2[jj] = __builtin_bit_cast(unsigned int, Ws[tx * 4 + jj][k2]);
            #pragma unroll
            for (int i = 0; i < 4; ++i)
                #pragma unroll
                for (int jj = 0; jj < 4; ++jj)
                    DOT2(acc[i][jj], w2[jj], a2[i]);
        }
    }
    #pragma unroll
    for (int jj = 0; jj < 4; ++jj) {
        float bb = bias[g0 + tx * 4 + jj];
        #pragma unroll
        for (int i = 0; i < 4; ++i) {
            int r = ty * 4 + i;
            Cs[r >> 4][tx * 4 + jj][r & 15] = __float2half(acc[i][jj] + bb);
        }
    }
    __syncthreads();
    for (int q = tid; q < 512; q += 256) {
        int dt = q >> 7, w128 = q & 127;
        uint4 v = ((const uint4*)&Cs[dt][0][0])[w128];
        __half* dst = out + (((size_t)bk * 1024 + tt * 4 + dt) * 768 + g0) * 16;
        ((uint4*)dst)[w128] = v;
    }
}

// GRU recurrence, full-M MFMA: 4 blocks x 16 batches; 512 threads = 8 waves.
// xw feed: per (sel,gate) ONE contiguous 512B wave-load (uint2/lane) from the
// transposed layout -- replaces round-15's 24 scalar gathers (the 12K-cyc
// stall). A/B/D fragment mappings verified numerically in rounds 14/15.
__global__ __launch_bounds__(512, 2)
void rec_kernel(const __half* __restrict__ wpack,  // [768][256] f16 row-major
                const float* __restrict__ b_hh,    // [768]
                const __half* __restrict__ xwt,    // [4][1024][768][16]
                __half* __restrict__ y) {          // [64][1024][256]
    __shared__ __align__(16) __half afrag[2][8][64][8];  // 16KB
    const int tid = threadIdx.x;
    const int w = tid >> 6, l = tid & 63;
    const int lm = l & 15, lk = l >> 4;
    const int bk = blockIdx.x;   // 0..3
    const int wb = w * 32;

    // B-fragments: [sel][gate][kt]; row = g*256 + wb + sel*16 + lm
    uint4 Bf[2][3][8];
    {
        const char* wb8 = (const char*)wpack;
        #pragma unroll
        for (int sel = 0; sel < 2; ++sel)
            #pragma unroll
            for (int g = 0; g < 3; ++g)
                #pragma unroll
                for (int kt = 0; kt < 8; ++kt) {
                    int gr = g * 256 + wb + sel * 16 + lm;
                    Bf[sel][g][kt] =
                        *(const uint4*)(wb8 + (size_t)gr * 512 + kt * 64 + lk * 16);
                    PINA4(Bf[sel][g][kt]);
                }
    }

    float bb[2][3];
    #pragma unroll
    for (int sel = 0; sel < 2; ++sel)
        #pragma unroll
        for (int g = 0; g < 3; ++g)
            bb[sel][g] = b_hh[g * 256 + wb + sel * 16 + lm];

    for (int idx = tid; idx < 1024; idx += 512)
        ((uint4*)afrag)[idx] = uint4{0u, 0u, 0u, 0u};

    const __half* xt = xwt + (size_t)bk * 1024 * 768 * 16;
    __half* yb[4];
    #pragma unroll
    for (int i = 0; i < 4; ++i)
        yb[i] = y + (size_t)(bk * 16 + lk * 4 + i) * 1024 * 256;

    float hp[2][4] = {};
    // prefetch t=0: uint2 = 4 batches (lk*4..+3) for (gu, this lane)
    uint2 nx[2][3];
    #pragma unroll
    for (int sel = 0; sel < 2; ++sel)
        #pragma unroll
        for (int g = 0; g < 3; ++g)
            nx[sel][g] = *(const uint2*)(xt +
                (size_t)(g * 256 + wb + sel * 16 + lm) * 16 + lk * 4);
    __syncthreads();

    for (int t = 0; t < 1024; ++t) {
        uint2 cx[2][3];
        #pragma unroll
        for (int sel = 0; sel < 2; ++sel)
            #pragma unroll
            for (int g = 0; g < 3; ++g)
                cx[sel][g] = nx[sel][g];
        // issue t+1 loads (t=1023 over-read lands in the adjacent ws region)
        {
            const __half* xq = xt + (size_t)(t + 1) * 768 * 16;
            #pragma unroll
            for (int sel = 0; sel < 2; ++sel)
                #pragma unroll
                for (int g = 0; g < 3; ++g)
                    nx[sel][g] = *(const uint2*)(xq +
                        (size_t)(g * 256 + wb + sel * 16 + lm) * 16 + lk * 4);
        }

        const __half* ab = &afrag[t & 1][0][0][0];
        f16x8 a[8];
        #pragma unroll
        for (int kt = 0; kt < 8; ++kt)
            a[kt] = *(const f16x8*)(ab + kt * 512 + l * 8);

        f32x4 acc[2][3];
        #pragma unroll
        for (int sel = 0; sel < 2; ++sel)
            #pragma unroll
            for (int g = 0; g < 3; ++g)
                acc[sel][g] = f32x4{0.f, 0.f, 0.f, 0.f};
        #pragma unroll
        for (int kt = 0; kt < 8; ++kt)
            #pragma unroll
            for (int sel = 0; sel < 2; ++sel)
                #pragma unroll
                for (int g = 0; g < 3; ++g)
                    acc[sel][g] = __builtin_amdgcn_mfma_f32_16x16x32_f16(
                        a[kt], __builtin_bit_cast(f16x8, Bf[sel][g][kt]),
                        acc[sel][g], 0, 0, 0);

        __half* nbuf = &afrag[(t + 1) & 1][0][0][0];
        #pragma unroll
        for (int sel = 0; sel < 2; ++sel) {
            const int u = wb + sel * 16 + lm;
            __half* aw = nbuf + (u >> 5) * 512 + ((u >> 3) & 3) * 128 + (u & 7);
            float xv[3][4];
            #pragma unroll
            for (int g = 0; g < 3; ++g) {
                float2 fa = __half22float2(__builtin_bit_cast(__half2, cx[sel][g].x));
                float2 fb = __half22float2(__builtin_bit_cast(__half2, cx[sel][g].y));
                xv[g][0] = fa.x; xv[g][1] = fa.y; xv[g][2] = fb.x; xv[g][3] = fb.y;
            }
            #pragma unroll
            for (int i = 0; i < 4; ++i) {
                float hr = acc[sel][0][i] + bb[sel][0];
                float hz = acc[sel][1][i] + bb[sel][1];
                float hn = acc[sel][2][i] + bb[sel][2];
                float r = fast_sigmoid(xv[0][i] + hr);
                float z = fast_sigmoid(xv[1][i] + hz);
                float pa = xv[2][i] + r * hn;
                pa = fminf(fmaxf(pa, -15.f), 15.f);
                float nn = fast_tanh_clamped(pa);
                float h = (1.f - z) * nn + z * hp[sel][i];
                hp[sel][i] = h;
                __half yh = __float2half(h);
                aw[(lk * 4 + i) * 8] = yh;                // frag-ordered h write
                yb[i][(size_t)t * 256 + u] = yh;          // stays in flight
            }
        }
        lds_barrier();   // LDS-only drain: xw loads / y stores not drained
    }
}

// Column stats (sum, sumsq) over [65536][256] f16
__global__ __launch_bounds__(256)
void bnstat(const __half* __restrict__ y, float* __restrict__ stats) {
    const int c = threadIdx.x;
    const size_t r0 = (size_t)blockIdx.x * 256;
    float s = 0.f, q = 0.f;
    for (int r = 0; r < 256; ++r) {
        float v = __half2float(y[(r0 + r) * 256 + c]);
        s += v; q += v * v;
    }
    atomicAdd(&stats[c], s);
    atomicAdd(&stats[256 + c], q);
}

// Layer-2: stats + per-(b,u) max/min over time
__global__ __launch_bounds__(256)
void bn2max(const __half* __restrict__ y, float* __restrict__ stats,
            float* __restrict__ mx_out, float* __restrict__ mn_out) {
    const int c = threadIdx.x, b = blockIdx.x;
    const __half* p = y + (size_t)b * 1024 * 256 + c;
    float s = 0.f, q = 0.f, M = -3e38f, m = 3e38f;
    for (int t = 0; t < 1024; ++t) {
        float v = __half2float(p[(size_t)t * 256]);
        s += v; q += v * v;
        M = fmaxf(M, v); m = fminf(m, v);
    }
    mx_out[b * 256 + c] = M;
    mn_out[b * 256 + c] = m;
    atomicAdd(&stats[c], s);
    atomicAdd(&stats[256 + c], q);
}

// Fold BN1 into layer-2 input weights.
__global__ void fold_bn1(const float* __restrict__ w_ih2, const float* __restrict__ b_ih2,
                         const float* __restrict__ g1, const float* __restrict__ be1,
                         const float* __restrict__ stats1,
                         __half* __restrict__ w_eff, float* __restrict__ b_eff) {
    const int g = blockIdx.x, lane = threadIdx.x;
    const float invN = 1.f / 65536.f;
    float partial = 0.f;
    for (int c = lane; c < 256; c += 64) {
        float mu = stats1[c] * invN;
        float var = stats1[256 + c] * invN - mu * mu;
        float s = g1[c] * rsqrtf(var + 1e-5f);
        float sh = be1[c] - mu * s;
        float w = w_ih2[g * 256 + c];
        w_eff[g * 256 + c] = __float2half(w * s);
        partial += w * sh;
    }
    #pragma unroll
    for (int off = 32; off > 0; off >>= 1) partial += __shfl_down(partial, off);
    if (lane == 0) b_eff[g] = b_ih2[g] + partial;
}

// BN2 affine -> time max-pool (sign-aware) -> tanh -> FC
__global__ void final_kernel(const float* __restrict__ stats2,
                             const float* __restrict__ mx, const float* __restrict__ mn,
                             const float* __restrict__ g2, const float* __restrict__ be2,
                             const float* __restrict__ w_fc, const float* __restrict__ b_fc,
                             float* __restrict__ out) {
    __shared__ float v[256];
    const int b = blockIdx.x, c = threadIdx.x;
    const float invN = 1.f / 65536.f;
    float mu = stats2[c] * invN;
    float var = stats2[256 + c] * invN - mu * mu;
    float s = g2[c] * rsqrtf(var + 1e-5f);
    float d = be2[c] - mu * s;
    float M = (s >= 0.f) ? mx[b * 256 + c] : mn[b * 256 + c];
    v[c] = tanhf(s * M + d);
    __syncthreads();
    if (c < 128) {
        float acc = b_fc[c];
        for (int k = 0; k < 256; ++k) acc += v[k] * w_fc[c * 256 + k];
        out[b * 128 + c] = acc;
    }
}

extern "C" void kernel_launch(void* const* d_in, const int* in_sizes, int n_in,
                              void* d_out, int out_size, void* d_ws, size_t ws_size,
                              hipStream_t stream) {
    const float* x     = (const float*)d_in[0];
    const float* w_ih1 = (const float*)d_in[1];
    const float* w_hh1 = (const float*)d_in[2];
    const float* b_ih1 = (const float*)d_in[3];
    const float* b_hh1 = (const float*)d_in[4];
    const float* g1    = (const float*)d_in[5];
    const float* be1   = (const float*)d_in[6];
    const float* w_ih2 = (const float*)d_in[7];
    const float* w_hh2 = (const float*)d_in[8];
    const float* b_ih2 = (const float*)d_in[9];
    const float* b_hh2 = (const float*)d_in[10];
    const float* g2    = (const float*)d_in[11];
    const float* be2   = (const float*)d_in[12];
    const float* w_fc  = (const float*)d_in[13];
    const float* b_fc  = (const float*)d_in[14];
    float* out = (float*)d_out;

    char* ws = (char*)d_ws;
    size_t off = 0;
    __half*  xwt  = (__half*)(ws + off);  off += (size_t)65536 * 768 * 2;  // transposed, shared by layers
    __half*  y1   = (__half*)(ws + off);  off += (size_t)65536 * 256 * 2;
    __half2* wp1  = (__half2*)(ws + off); off += (size_t)768 * 128 * 4;
    __half2* wp2  = (__half2*)(ws + off); off += (size_t)768 * 128 * 4;
    __half*  weff = (__half*)(ws + off);  off += (size_t)768 * 256 * 2;
    float*   beff = (float*)(ws + off);   off += (size_t)768 * 4;
    float*   stats= (float*)(ws + off);   off += (size_t)1024 * 4;
    float*   mx2  = (float*)(ws + off);   off += (size_t)64 * 256 * 4;
    float*   mn2  = (float*)(ws + off);   off += (size_t)64 * 256 * 4;

    (void)hipMemsetAsync(stats, 0, 4096, stream);

    pack_whh<<<dim3(768, 2), dim3(128), 0, stream>>>(w_hh1, w_hh2, wp1, wp2);
    gemm_xw1<<<dim3(12, 1024), dim3(256), 0, stream>>>(x, w_ih1, b_ih1, xwt);
    rec_kernel<<<dim3(4), dim3(512), 0, stream>>>((const __half*)wp1, b_hh1, xwt, y1);
    bnstat<<<dim3(256), dim3(256), 0, stream>>>(y1, stats);
    fold_bn1<<<dim3(768), dim3(64), 0, stream>>>(w_ih2, b_ih2, g1, be1, stats, weff, beff);
    gemm_xw2<<<dim3(12, 1024), dim3(256), 0, stream>>>((const __half2*)y1, (const __half2*)weff,
                                                       beff, xwt);
    rec_kernel<<<dim3(4), dim3(512), 0, stream>>>((const __half*)wp2, b_hh2, xwt, y1);
    bn2max<<<dim3(64), dim3(256), 0, stream>>>(y1, stats + 512, mx2, mn2);
    final_kernel<<<dim3(64), dim3(256), 0, stream>>>(stats + 512, mx2, mn2, g2, be2,
                                                     w_fc, b_fc, out);
}

// Round 18
// 9194.926 us; speedup vs baseline: 1.2065x; 1.0503x over previous
//
#include <hip/hip_runtime.h>
#include <hip/hip_fp16.h>
#include <cstdint>
#include <cstddef>

// Sizes: B=64, T=1024, I=64, H=256, G=3H=768, N=B*T=65536
// xwt layout (TRANSPOSED for rec): [16 bk][1024 t][768 gu][4 bi] f16,
// bi = batch&3, bk = batch>>2.

typedef _Float16 f16x8 __attribute__((ext_vector_type(8)));
typedef float f32x4 __attribute__((ext_vector_type(4)));

#define DOT2(acc, w, h) \
    asm("v_dot2_f32_f16 %0, %1, %2, %0" : "+v"(acc) : "v"(w), "v"(h))

// Pin weight words into AGPRs: loads hoist once, MFMA reads AGPRs natively.
#define PINA(x) asm volatile("" : "+a"(x))
#define PINA4(q) do { PINA(q.x); PINA(q.y); PINA(q.z); PINA(q.w); } while (0)

// LDS-only barrier: do NOT drain vmcnt (global loads/stores stay in flight).
__device__ __forceinline__ void lds_barrier() {
    asm volatile("s_waitcnt lgkmcnt(0)\n\ts_barrier" ::: "memory");
}

__device__ __forceinline__ float fast_sigmoid(float x) {
    float t = x * -1.4426950408889634f, e, r;
    asm("v_exp_f32 %0, %1" : "=v"(e) : "v"(t));
    float d = 1.f + e;
    asm("v_rcp_f32 %0, %1" : "=v"(r) : "v"(d));
    return r;
}
__device__ __forceinline__ float fast_tanh_clamped(float x) {  // |x| <= 15
    float t = x * 2.8853900817779268f, e, r;
    asm("v_exp_f32 %0, %1" : "=v"(e) : "v"(t));
    float d = e + 1.f;
    asm("v_rcp_f32 %0, %1" : "=v"(r) : "v"(d));
    return 1.f - 2.f * r;
}

// Pack w_hh [768][256] f32 -> f16 row-major [768][256]
__global__ void pack_whh(const float* __restrict__ w1, const float* __restrict__ w2,
                         __half2* __restrict__ o1, __half2* __restrict__ o2) {
    int g = blockIdx.x;
    int k2 = threadIdx.x;
    const float* w = blockIdx.y ? w2 : w1;
    __half2* o = blockIdx.y ? o2 : o1;
    float a = w[g * 256 + 2 * k2];
    float b = w[g * 256 + 2 * k2 + 1];
    o[g * 128 + k2] = __floats2half2_rn(a, b);
}

// xw1: x[65536,64] @ w_ih1[768,64]^T + b -> xwt [16][1024][768][4].
// n-tile of 64 rows = {4 bi x 16 dt}; epilogue stages C in LDS, writes
// 512B-contiguous chunks per dt.
__global__ __launch_bounds__(256)
void gemm_xw1(const float* __restrict__ A, const float* __restrict__ W,
              const float* __restrict__ bias, __half* __restrict__ out) {
    __shared__ float As[64][65];
    __shared__ float Ws[64][65];
    __shared__ __align__(16) __half Cs[16][64][4];
    const int tid = threadIdx.x;
    const int g0 = blockIdx.x * 64;
    const int bk = blockIdx.y >> 6, tt = blockIdx.y & 63;
    for (int idx = tid; idx < 4096; idx += 256) {
        int r = idx >> 6, c = idx & 63;
        int n = (bk * 4 + (r & 3)) * 1024 + tt * 16 + (r >> 2);
        As[r][c] = A[(size_t)n * 64 + c];
        Ws[r][c] = W[(size_t)(g0 + r) * 64 + c];
    }
    __syncthreads();
    const int ty = tid >> 4, tx = tid & 15;
    float acc[4][4] = {};
    for (int k = 0; k < 64; ++k) {
        float a[4], w[4];
        #pragma unroll
        for (int i = 0; i < 4; ++i) a[i] = As[ty * 4 + i][k];
        #pragma unroll
        for (int jj = 0; jj < 4; ++jj) w[jj] = Ws[tx * 4 + jj][k];
        #pragma unroll
        for (int i = 0; i < 4; ++i)
            #pragma unroll
            for (int jj = 0; jj < 4; ++jj) acc[i][jj] += a[i] * w[jj];
    }
    #pragma unroll
    for (int jj = 0; jj < 4; ++jj) {
        float bb = bias[g0 + tx * 4 + jj];
        #pragma unroll
        for (int i = 0; i < 4; ++i) {
            int r = ty * 4 + i;
            Cs[r >> 2][tx * 4 + jj][r & 3] = __float2half(acc[i][jj] + bb);
        }
    }
    __syncthreads();
    // 16 dt x (64 gu x 4 bi) = 16 x 512B contiguous
    for (int q = tid; q < 512; q += 256) {
        int dt = q >> 5, w32 = q & 31;
        uint4 v = ((const uint4*)&Cs[dt][0][0])[w32];
        __half* dst = out + (((size_t)bk * 1024 + tt * 16 + dt) * 768 + g0) * 4;
        ((uint4*)dst)[w32] = v;
    }
}

// xw2: y1[65536,256](f16) @ w_eff[768,256]^T + b_eff -> xwt layout.
__global__ __launch_bounds__(256)
void gemm_xw2(const __half2* __restrict__ A, const __half2* __restrict__ W,
              const float* __restrict__ bias, __half* __restrict__ out) {
    __shared__ __half2 As[64][33];
    __shared__ __half2 Ws[64][33];
    __shared__ __align__(16) __half Cs[16][64][4];
    const int tid = threadIdx.x;
    const int g0 = blockIdx.x * 64;
    const int bk = blockIdx.y >> 6, tt = blockIdx.y & 63;
    const int ty = tid >> 4, tx = tid & 15;
    float acc[4][4] = {};
    for (int kc = 0; kc < 4; ++kc) {
        __syncthreads();
        for (int idx = tid; idx < 2048; idx += 256) {
            int r = idx >> 5, c2 = idx & 31;
            int n = (bk * 4 + (r & 3)) * 1024 + tt * 16 + (r >> 2);
            As[r][c2] = A[(size_t)n * 128 + kc * 32 + c2];
            Ws[r][c2] = W[(size_t)(g0 + r) * 128 + kc * 32 + c2];
        }
        __syncthreads();
        #pragma unroll 8
        for (int k2 = 0; k2 < 32; ++k2) {
            unsigned int a2[4], w2[4];
            #pragma unroll
            for (int i = 0; i < 4; ++i)
                a2[i] = __builtin_bit_cast(unsigned int, As[ty * 4 + i][k2]);
            #pragma unroll
            for (int jj = 0; jj < 4; ++jj)
                w2[jj] = __builtin_bit_cast(unsigned int, Ws[tx * 4 + jj][k2]);
            #pragma unroll
            for (int i = 0; i < 4; ++i)
                #pragma unroll
                for (int jj = 0; jj < 4; ++jj)
                    DOT2(acc[i][jj], w2[jj], a2[i]);
        }
    }
    #pragma unroll
    for (int jj = 0; jj < 4; ++jj) {
        float bb = bias[g0 + tx * 4 + jj];
        #pragma unroll
        for (int i = 0; i < 4; ++i) {
            int r = ty * 4 + i;
            Cs[r >> 2][tx * 4 + jj][r & 3] = __float2half(acc[i][jj] + bb);
        }
    }
    __syncthreads();
    for (int q = tid; q < 512; q += 256) {
        int dt = q >> 5, w32 = q & 31;
        uint4 v = ((const uint4*)&Cs[dt][0][0])[w32];
        __half* dst = out + (((size_t)bk * 1024 + tt * 16 + dt) * 768 + g0) * 4;
        ((uint4*)dst)[w32] = v;
    }
}

// GRU recurrence: 16 blocks x 4 batches (M=4 of the 16x16 MFMA tile; rows
// 4-15 zero -- matrix pipe was 14% busy, wasting it is free). 512 thr = 8
// waves; wave w owns units [w*32,(w+1)*32) as 48 AGPR B-fragments.
// xw feed: 6 x 128B line-loads/wave/step (48 lines/CU/step, 4x less than
// round 17) + DEPTH-2 prefetch ring (pA/pB, loop unrolled 2x, static idx).
// Nonlinearity on lk==0 lanes (4 batches x 2 units each).
__global__ __launch_bounds__(512, 2)
void rec_kernel(const __half* __restrict__ wpack,  // [768][256] f16 row-major
                const float* __restrict__ b_hh,    // [768]
                const __half* __restrict__ xwt,    // [16][1024][768][4]
                __half* __restrict__ y) {          // [64][1024][256]
    __shared__ __align__(16) __half afrag[2][8][64][8];  // 16KB
    const int tid = threadIdx.x;
    const int w = tid >> 6, l = tid & 63;
    const int lm = l & 15, lk = l >> 4;
    const int bk = blockIdx.x;   // 0..15
    const int wb = w * 32;

    uint4 Bf[2][3][8];
    {
        const char* wb8 = (const char*)wpack;
        #pragma unroll
        for (int sel = 0; sel < 2; ++sel)
            #pragma unroll
            for (int g = 0; g < 3; ++g)
                #pragma unroll
                for (int kt = 0; kt < 8; ++kt) {
                    int gr = g * 256 + wb + sel * 16 + lm;
                    Bf[sel][g][kt] =
                        *(const uint4*)(wb8 + (size_t)gr * 512 + kt * 64 + lk * 16);
                    PINA4(Bf[sel][g][kt]);
                }
    }

    float bb[2][3];
    #pragma unroll
    for (int sel = 0; sel < 2; ++sel)
        #pragma unroll
        for (int g = 0; g < 3; ++g)
            bb[sel][g] = b_hh[g * 256 + wb + sel * 16 + lm];

    for (int idx = tid; idx < 1024; idx += 512)
        ((uint4*)afrag)[idx] = uint4{0u, 0u, 0u, 0u};

    const __half* xt = xwt + (size_t)bk * 1024 * 768 * 4;
    __half* yb[4];
    #pragma unroll
    for (int i = 0; i < 4; ++i)
        yb[i] = y + (size_t)(bk * 4 + i) * 1024 * 256;

    float hp[2][4] = {};

    // depth-2 prefetch ring: pA holds even-t, pB odd-t. uint2 = 4 batches.
    uint2 pA[2][3], pB[2][3];
    #pragma unroll
    for (int sel = 0; sel < 2; ++sel)
        #pragma unroll
        for (int g = 0; g < 3; ++g) {
            size_t gu = (size_t)(g * 256 + wb + sel * 16 + lm) * 4;
            pA[sel][g] = *(const uint2*)(xt + gu);                 // t=0
            pB[sel][g] = *(const uint2*)(xt + (size_t)768 * 4 + gu); // t=1
        }
    __syncthreads();

    #define REC_STEP(T, PBUF)                                                  \
    {                                                                          \
        uint2 cx[2][3];                                                        \
        _Pragma("unroll")                                                      \
        for (int sel = 0; sel < 2; ++sel)                                      \
            _Pragma("unroll")                                                  \
            for (int g = 0; g < 3; ++g) cx[sel][g] = PBUF[sel][g];             \
        {   /* issue loads for T+2 */                                          \
            const __half* xq = xt + (size_t)((T) + 2) * 768 * 4;               \
            _Pragma("unroll")                                                  \
            for (int sel = 0; sel < 2; ++sel)                                  \
                _Pragma("unroll")                                              \
                for (int g = 0; g < 3; ++g)                                    \
                    PBUF[sel][g] = *(const uint2*)(xq +                        \
                        (size_t)(g * 256 + wb + sel * 16 + lm) * 4);           \
        }                                                                      \
        const __half* ab = &afrag[(T) & 1][0][0][0];                           \
        f16x8 a[8];                                                            \
        _Pragma("unroll")                                                      \
        for (int kt = 0; kt < 8; ++kt)                                         \
            a[kt] = *(const f16x8*)(ab + kt * 512 + l * 8);                    \
        f32x4 acc[2][3];                                                       \
        _Pragma("unroll")                                                      \
        for (int sel = 0; sel < 2; ++sel)                                      \
            _Pragma("unroll")                                                  \
            for (int g = 0; g < 3; ++g) acc[sel][g] = f32x4{0.f,0.f,0.f,0.f};  \
        _Pragma("unroll")                                                      \
        for (int kt = 0; kt < 8; ++kt)                                         \
            _Pragma("unroll")                                                  \
            for (int sel = 0; sel < 2; ++sel)                                  \
                _Pragma("unroll")                                              \
                for (int g = 0; g < 3; ++g)                                    \
                    acc[sel][g] = __builtin_amdgcn_mfma_f32_16x16x32_f16(      \
                        a[kt], __builtin_bit_cast(f16x8, Bf[sel][g][kt]),      \
                        acc[sel][g], 0, 0, 0);                                 \
        __half* nbuf = &afrag[((T) + 1) & 1][0][0][0];                         \
        if (lk == 0) {                                                         \
            _Pragma("unroll")                                                  \
            for (int sel = 0; sel < 2; ++sel) {                                \
                const int u = wb + sel * 16 + lm;                              \
                __half* aw = nbuf + (u >> 5) * 512 + ((u >> 3) & 3) * 128 +    \
                             (u & 7);                                          \
                float xv[3][4];                                                \
                _Pragma("unroll")                                              \
                for (int g = 0; g < 3; ++g) {                                  \
                    float2 fa = __half22float2(                                \
                        __builtin_bit_cast(__half2, cx[sel][g].x));            \
                    float2 fb = __half22float2(                                \
                        __builtin_bit_cast(__half2, cx[sel][g].y));            \
                    xv[g][0] = fa.x; xv[g][1] = fa.y;                          \
                    xv[g][2] = fb.x; xv[g][3] = fb.y;                          \
                }                                                              \
                _Pragma("unroll")                                              \
                for (int i = 0; i < 4; ++i) {                                  \
                    float hr = acc[sel][0][i] + bb[sel][0];                    \
                    float hz = acc[sel][1][i] + bb[sel][1];                    \
                    float hn = acc[sel][2][i] + bb[sel][2];                    \
                    float r = fast_sigmoid(xv[0][i] + hr);                     \
                    float z = fast_sigmoid(xv[1][i] + hz);                     \
                    float pa = xv[2][i] + r * hn;                              \
                    pa = fminf(fmaxf(pa, -15.f), 15.f);                        \
                    float nn = fast_tanh_clamped(pa);                          \
                    float h = (1.f - z) * nn + z * hp[sel][i];                 \
                    hp[sel][i] = h;                                            \
                    __half yh = __float2half(h);                               \
                    aw[i * 8] = yh;                                            \
                    yb[i][(size_t)(T) * 256 + u] = yh;                         \
                }                                                              \
            }                                                                  \
        }                                                                      \
        lds_barrier();                                                         \
    }

    for (int t = 0; t < 1024; t += 2) {
        REC_STEP(t, pA);
        REC_STEP(t + 1, pB);
    }
    #undef REC_STEP
}

// Column stats (sum, sumsq) over [65536][256] f16
__global__ __launch_bounds__(256)
void bnstat(const __half* __restrict__ y, float* __restrict__ stats) {
    const int c = threadIdx.x;
    const size_t r0 = (size_t)blockIdx.x * 256;
    float s = 0.f, q = 0.f;
    for (int r = 0; r < 256; ++r) {
        float v = __half2float(y[(r0 + r) * 256 + c]);
        s += v; q += v * v;
    }
    atomicAdd(&stats[c], s);
    atomicAdd(&stats[256 + c], q);
}

// Layer-2: stats + per-(b,u) max/min over time
__global__ __launch_bounds__(256)
void bn2max(const __half* __restrict__ y, float* __restrict__ stats,
            float* __restrict__ mx_out, float* __restrict__ mn_out) {
    const int c = threadIdx.x, b = blockIdx.x;
    const __half* p = y + (size_t)b * 1024 * 256 + c;
    float s = 0.f, q = 0.f, M = -3e38f, m = 3e38f;
    for (int t = 0; t < 1024; ++t) {
        float v = __half2float(p[(size_t)t * 256]);
        s += v; q += v * v;
        M = fmaxf(M, v); m = fminf(m, v);
    }
    mx_out[b * 256 + c] = M;
    mn_out[b * 256 + c] = m;
    atomicAdd(&stats[c], s);
    atomicAdd(&stats[256 + c], q);
}

// Fold BN1 into layer-2 input weights.
__global__ void fold_bn1(const float* __restrict__ w_ih2, const float* __restrict__ b_ih2,
                         const float* __restrict__ g1, const float* __restrict__ be1,
                         const float* __restrict__ stats1,
                         __half* __restrict__ w_eff, float* __restrict__ b_eff) {
    const int g = blockIdx.x, lane = threadIdx.x;
    const float invN = 1.f / 65536.f;
    float partial = 0.f;
    for (int c = lane; c < 256; c += 64) {
        float mu = stats1[c] * invN;
        float var = stats1[256 + c] * invN - mu * mu;
        float s = g1[c] * rsqrtf(var + 1e-5f);
        float sh = be1[c] - mu * s;
        float w = w_ih2[g * 256 + c];
        w_eff[g * 256 + c] = __float2half(w * s);
        partial += w * sh;
    }
    #pragma unroll
    for (int off = 32; off > 0; off >>= 1) partial += __shfl_down(partial, off);
    if (lane == 0) b_eff[g] = b_ih2[g] + partial;
}

// BN2 affine -> time max-pool (sign-aware) -> tanh -> FC
__global__ void final_kernel(const float* __restrict__ stats2,
                             const float* __restrict__ mx, const float* __restrict__ mn,
                             const float* __restrict__ g2, const float* __restrict__ be2,
                             const float* __restrict__ w_fc, const float* __restrict__ b_fc,
                             float* __restrict__ out) {
    __shared__ float v[256];
    const int b = blockIdx.x, c = threadIdx.x;
    const float invN = 1.f / 65536.f;
    float mu = stats2[c] * invN;
    float var = stats2[256 + c] * invN - mu * mu;
    float s = g2[c] * rsqrtf(var + 1e-5f);
    float d = be2[c] - mu * s;
    float M = (s >= 0.f) ? mx[b * 256 + c] : mn[b * 256 + c];
    v[c] = tanhf(s * M + d);
    __syncthreads();
    if (c < 128) {
        float acc = b_fc[c];
        for (int k = 0; k < 256; ++k) acc += v[k] * w_fc[c * 256 + k];
        out[b * 128 + c] = acc;
    }
}

extern "C" void kernel_launch(void* const* d_in, const int* in_sizes, int n_in,
                              void* d_out, int out_size, void* d_ws, size_t ws_size,
                              hipStream_t stream) {
    const float* x     = (const float*)d_in[0];
    const float* w_ih1 = (const float*)d_in[1];
    const float* w_hh1 = (const float*)d_in[2];
    const float* b_ih1 = (const float*)d_in[3];
    const float* b_hh1 = (const float*)d_in[4];
    const float* g1    = (const float*)d_in[5];
    const float* be1   = (const float*)d_in[6];
    const float* w_ih2 = (const float*)d_in[7];
    const float* w_hh2 = (const float*)d_in[8];
    const float* b_ih2 = (const float*)d_in[9];
    const float* b_hh2 = (const float*)d_in[10];
    const float* g2    = (const float*)d_in[11];
    const float* be2   = (const float*)d_in[12];
    const float* w_fc  = (const float*)d_in[13];
    const float* b_fc  = (const float*)d_in[14];
    float* out = (float*)d_out;

    char* ws = (char*)d_ws;
    size_t off = 0;
    __half*  xwt  = (__half*)(ws + off);  off += (size_t)65536 * 768 * 2;  // transposed, shared by layers
    __half*  y1   = (__half*)(ws + off);  off += (size_t)65536 * 256 * 2;
    __half2* wp1  = (__half2*)(ws + off); off += (size_t)768 * 128 * 4;
    __half2* wp2  = (__half2*)(ws + off); off += (size_t)768 * 128 * 4;
    __half*  weff = (__half*)(ws + off);  off += (size_t)768 * 256 * 2;
    float*   beff = (float*)(ws + off);   off += (size_t)768 * 4;
    float*   stats= (float*)(ws + off);   off += (size_t)1024 * 4;
    float*   mx2  = (float*)(ws + off);   off += (size_t)64 * 256 * 4;
    float*   mn2  = (float*)(ws + off);   off += (size_t)64 * 256 * 4;

    (void)hipMemsetAsync(stats, 0, 4096, stream);

    pack_whh<<<dim3(768, 2), dim3(128), 0, stream>>>(w_hh1, w_hh2, wp1, wp2);
    gemm_xw1<<<dim3(12, 1024), dim3(256), 0, stream>>>(x, w_ih1, b_ih1, xwt);
    rec_kernel<<<dim3(16), dim3(512), 0, stream>>>((const __half*)wp1, b_hh1, xwt, y1);
    bnstat<<<dim3(256), dim3(256), 0, stream>>>(y1, stats);
    fold_bn1<<<dim3(768), dim3(64), 0, stream>>>(w_ih2, b_ih2, g1, be1, stats, weff, beff);
    gemm_xw2<<<dim3(12, 1024), dim3(256), 0, stream>>>((const __half2*)y1, (const __half2*)weff,
                                                       beff, xwt);
    rec_kernel<<<dim3(16), dim3(512), 0, stream>>>((const __half*)wp2, b_hh2, xwt, y1);
    bn2max<<<dim3(64), dim3(256), 0, stream>>>(y1, stats + 512, mx2, mn2);
    final_kernel<<<dim3(64), dim3(256), 0, stream>>>(stats + 512, mx2, mn2, g2, be2,
                                                     w_fc, b_fc, out);
}

// Round 19
// 2858.802 us; speedup vs baseline: 3.8806x; 3.2164x over previous
//
#include <hip/hip_runtime.h>
#include <hip/hip_fp16.h>
#include <cstdint>
#include <cstddef>

// Sizes (fixed by the problem)
// B=64, T=1024, I=64, H=256, G=3H=768, N=B*T=65536

// Pinned v_dot2_f32_f16: acc += w.h[0]*h.h[0] + w.h[1]*h.h[1]
#define DOT2(acc, w, h) \
    asm("v_dot2_f32_f16 %0, %1, %2, %0" : "+v"(acc) : "v"(w), "v"(h))

// DPP quad-perm butterfly add. 0xB1 = xor1 within quad, 0x4E = xor2.
template<int CTL>
__device__ __forceinline__ float dpp_add(float x) {
    int t = __builtin_amdgcn_update_dpp(0, __builtin_bit_cast(int, x),
                                        CTL, 0xF, 0xF, true);
    return x + __builtin_bit_cast(float, t);
}

// LDS-only barrier: do NOT drain vmcnt (global loads/stores stay in flight).
__device__ __forceinline__ void lds_barrier() {
    asm volatile("s_waitcnt lgkmcnt(0)\n\ts_barrier" ::: "memory");
}

// Fast transcendentals: raw v_exp (2^x) + v_rcp -- avoids the ~10-instr IEEE
// f32 divide expansion of 1/(1+expf(x)). Args bounded (pre-activations
// clamped); rcp ~1e-7 relative, harmless vs f16 storage.
__device__ __forceinline__ float fast_sigmoid(float x) {
    float t = x * -1.4426950408889634f, e, r;
    asm("v_exp_f32 %0, %1" : "=v"(e) : "v"(t));
    float d = 1.f + e;
    asm("v_rcp_f32 %0, %1" : "=v"(r) : "v"(d));
    return r;
}
__device__ __forceinline__ float fast_tanh_clamped(float x) {  // |x| <= 15
    float t = x * 2.8853900817779268f, e, r;                   // 2*log2(e)
    asm("v_exp_f32 %0, %1" : "=v"(e) : "v"(t));                // e^(2x)
    float d = e + 1.f;
    asm("v_rcp_f32 %0, %1" : "=v"(r) : "v"(d));
    return 1.f - 2.f * r;
}

// Pack w_hh [768][256] f32 -> [768][128] of f16-pairs (adjacent k packed)
__global__ void pack_whh(const float* __restrict__ w1, const float* __restrict__ w2,
                         __half2* __restrict__ o1, __half2* __restrict__ o2) {
    int g = blockIdx.x;       // 0..767
    int k2 = threadIdx.x;     // 0..127
    const float* w = blockIdx.y ? w2 : w1;
    __half2* o = blockIdx.y ? o2 : o1;
    float a = w[g * 256 + 2 * k2];
    float b = w[g * 256 + 2 * k2 + 1];
    o[g * 128 + k2] = __floats2half2_rn(a, b);
}

// xw1 = x[65536,64] @ w_ih1[768,64]^T + b_ih1 -> f16 [65536,768]
__global__ __launch_bounds__(256)
void gemm_xw1(const float* __restrict__ A, const float* __restrict__ W,
              const float* __restrict__ bias, __half* __restrict__ out) {
    __shared__ float As[64][65];
    __shared__ float Ws[64][65];
    const int tid = threadIdx.x;
    const int n0 = blockIdx.y * 64, g0 = blockIdx.x * 64;
    for (int idx = tid; idx < 4096; idx += 256) {
        int r = idx >> 6, c = idx & 63;
        As[r][c] = A[(size_t)(n0 + r) * 64 + c];
        Ws[r][c] = W[(size_t)(g0 + r) * 64 + c];
    }
    __syncthreads();
    const int ty = tid >> 4, tx = tid & 15;
    float acc[4][4] = {};
    for (int k = 0; k < 64; ++k) {
        float a[4], w[4];
        #pragma unroll
        for (int i = 0; i < 4; ++i) a[i] = As[ty * 4 + i][k];
        #pragma unroll
        for (int jj = 0; jj < 4; ++jj) w[jj] = Ws[tx * 4 + jj][k];
        #pragma unroll
        for (int i = 0; i < 4; ++i)
            #pragma unroll
            for (int jj = 0; jj < 4; ++jj) acc[i][jj] += a[i] * w[jj];
    }
    #pragma unroll
    for (int jj = 0; jj < 4; ++jj) {
        float bb = bias[g0 + tx * 4 + jj];
        #pragma unroll
        for (int i = 0; i < 4; ++i)
            out[(size_t)(n0 + ty * 4 + i) * 768 + (g0 + tx * 4 + jj)] =
                __float2half(acc[i][jj] + bb);
    }
}

// xw2 = y1[65536,256](f16) @ w_eff[768,256](f16)^T + b_eff -> f16 [65536,768]
__global__ __launch_bounds__(256)
void gemm_xw2(const __half2* __restrict__ A, const __half2* __restrict__ W,
              const float* __restrict__ bias, __half* __restrict__ out) {
    __shared__ __half2 As[64][33];
    __shared__ __half2 Ws[64][33];
    const int tid = threadIdx.x;
    const int n0 = blockIdx.y * 64, g0 = blockIdx.x * 64;
    const int ty = tid >> 4, tx = tid & 15;
    float acc[4][4] = {};
    for (int kc = 0; kc < 4; ++kc) {
        __syncthreads();
        for (int idx = tid; idx < 2048; idx += 256) {
            int r = idx >> 5, c2 = idx & 31;
            As[r][c2] = A[(size_t)(n0 + r) * 128 + kc * 32 + c2];
            Ws[r][c2] = W[(size_t)(g0 + r) * 128 + kc * 32 + c2];
        }
        __syncthreads();
        #pragma unroll 8
        for (int k2 = 0; k2 < 32; ++k2) {
            unsigned int a2[4], w2[4];
            #pragma unroll
            for (int i = 0; i < 4; ++i)
                a2[i] = __builtin_bit_cast(unsigned int, As[ty * 4 + i][k2]);
            #pragma unroll
            for (int jj = 0; jj < 4; ++jj)
                w2[jj] = __builtin_bit_cast(unsigned int, Ws[tx * 4 + jj][k2]);
            #pragma unroll
            for (int i = 0; i < 4; ++i)
                #pragma unroll
                for (int jj = 0; jj < 4; ++jj)
                    DOT2(acc[i][jj], w2[jj], a2[i]);
        }
    }
    #pragma unroll
    for (int jj = 0; jj < 4; ++jj) {
        float bb = bias[g0 + tx * 4 + jj];
        #pragma unroll
        for (int i = 0; i < 4; ++i)
            out[(size_t)(n0 + ty * 4 + i) * 768 + (g0 + tx * 4 + jj)] =
                __float2half(acc[i][jj] + bb);
    }
}

// GRU recurrence, 2-units x K-quarter partition (round-11 structure, the
// best-measured config: 64 CUs, VALU dot2, 1263us/layer): 512 threads/block;
// thread = (pair p = tid>>2, K-quarter kq = tid&3); owns units {2p, 2p+1}.
// Weights: 192 regs/thread loaded once. DPP quad butterfly reduction.
// LDS-only barrier keeps global traffic in flight. This round: fast
// transcendentals replace expf + IEEE-div in the gate nonlinearity.
template<int LAYER>
__global__ __launch_bounds__(512, 2)
void rec_kernel(const __half2* __restrict__ wpack,  // [768][128] f16-pairs
                const float* __restrict__ b_hh,     // [768]
                const __half* __restrict__ xw,      // [64][1024][768]
                __half* __restrict__ y_out,         // LAYER==1: [64][1024][256]
                float* __restrict__ stats,          // sum[256], sumsq[256]
                float* __restrict__ mx_out,         // LAYER==2: [64][256]
                float* __restrict__ mn_out) {
    __shared__ __align__(16) uint4 hb4[2][4][9];   // [buf][K-quarter][8 uint4 + pad]
    const int tid = threadIdx.x;   // 0..511
    const int p   = tid >> 2;      // unit pair 0..127
    const int kq  = tid & 3;       // K-quarter
    const int kql = kq & 1;
    const int u   = 2 * p + kql;   // tail unit this lane finishes
    const int b   = blockIdx.x;    // 0..63

    // Weight fragments: rows {2p,2p+1} x gates {r,z,n}, K-quarter kq.
    uint4 Wr0[8], Wr1[8], Wz0[8], Wz1[8], Wn0[8], Wn1[8];
    {
        const uint4* wp4 = (const uint4*)wpack;
        const int mb = kq * 8;
        #pragma unroll
        for (int m = 0; m < 8; ++m) Wr0[m] = wp4[(size_t)(2 * p) * 32 + mb + m];
        #pragma unroll
        for (int m = 0; m < 8; ++m) Wr1[m] = wp4[(size_t)(2 * p + 1) * 32 + mb + m];
        #pragma unroll
        for (int m = 0; m < 8; ++m) Wz0[m] = wp4[(size_t)(2 * p + 256) * 32 + mb + m];
        #pragma unroll
        for (int m = 0; m < 8; ++m) Wz1[m] = wp4[(size_t)(2 * p + 257) * 32 + mb + m];
        #pragma unroll
        for (int m = 0; m < 8; ++m) Wn0[m] = wp4[(size_t)(2 * p + 512) * 32 + mb + m];
        #pragma unroll
        for (int m = 0; m < 8; ++m) Wn1[m] = wp4[(size_t)(2 * p + 513) * 32 + mb + m];
    }

    const float bru = b_hh[u], bzu = b_hh[256 + u], bnu = b_hh[512 + u];

    if (tid < 36) ((uint4*)hb4)[tid] = uint4{0u, 0u, 0u, 0u};  // zero buffer 0

    float hprev = 0.f, ssum = 0.f, ssq = 0.f;
    float mx = -3.0e38f, mn = 3.0e38f;
    const __half* xwp = xw + (size_t)b * 1024 * 768;
    __half* yp = (LAYER == 1) ? (y_out + (size_t)b * 1024 * 256) : (__half*)nullptr;

    // prefetch t=0 (lanes kq=2,3 mirror kq=0,1 -- same cacheline)
    __half nxr = xwp[u], nxz = xwp[256 + u], nxn = xwp[512 + u];
    __syncthreads();

    for (int t = 0; t < 1024; ++t) {
        __half cxr = nxr, cxz = nxz, cxn = nxn;
        // prefetch t+1 (t=1023 over-read lands in the adjacent ws region; discarded)
        const __half* xq = xwp + (size_t)(t + 1) * 768;
        nxr = xq[u]; nxz = xq[256 + u]; nxn = xq[512 + u];

        float r0 = 0.f, r1 = 0.f, z0 = 0.f, z1 = 0.f, n0 = 0.f, n1 = 0.f;
        const uint4* hq = hb4[t & 1][kq];
        #pragma unroll
        for (int m = 0; m < 8; ++m) {
            uint4 h = hq[m];
            DOT2(r0, Wr0[m].x, h.x);
            DOT2(r1, Wr1[m].x, h.x);
            DOT2(z0, Wz0[m].x, h.x);
            DOT2(z1, Wz1[m].x, h.x);
            DOT2(n0, Wn0[m].x, h.x);
            DOT2(n1, Wn1[m].x, h.x);
            DOT2(r0, Wr0[m].y, h.y);
            DOT2(r1, Wr1[m].y, h.y);
            DOT2(z0, Wz0[m].y, h.y);
            DOT2(z1, Wz1[m].y, h.y);
            DOT2(n0, Wn0[m].y, h.y);
            DOT2(n1, Wn1[m].y, h.y);
            DOT2(r0, Wr0[m].z, h.z);
            DOT2(r1, Wr1[m].z, h.z);
            DOT2(z0, Wz0[m].z, h.z);
            DOT2(z1, Wz1[m].z, h.z);
            DOT2(n0, Wn0[m].z, h.z);
            DOT2(n1, Wn1[m].z, h.z);
            DOT2(r0, Wr0[m].w, h.w);
            DOT2(r1, Wr1[m].w, h.w);
            DOT2(z0, Wz0[m].w, h.w);
            DOT2(z1, Wz1[m].w, h.w);
            DOT2(n0, Wn0[m].w, h.w);
            DOT2(n1, Wn1[m].w, h.w);
        }
        // combine K-quarters within the 4-lane quad (DPP butterfly, VALU-only)
        r0 = dpp_add<0xB1>(r0); r0 = dpp_add<0x4E>(r0);
        r1 = dpp_add<0xB1>(r1); r1 = dpp_add<0x4E>(r1);
        z0 = dpp_add<0xB1>(z0); z0 = dpp_add<0x4E>(z0);
        z1 = dpp_add<0xB1>(z1); z1 = dpp_add<0x4E>(z1);
        n0 = dpp_add<0xB1>(n0); n0 = dpp_add<0x4E>(n0);
        n1 = dpp_add<0xB1>(n1); n1 = dpp_add<0x4E>(n1);

        float hr = (kql ? r1 : r0) + bru;
        float hz = (kql ? z1 : z0) + bzu;
        float hn = (kql ? n1 : n0) + bnu;

        float xr = __half2float(cxr);
        float xz = __half2float(cxz);
        float xn = __half2float(cxn);
        float r = fast_sigmoid(xr + hr);
        float z = fast_sigmoid(xz + hz);
        float pa = xn + r * hn;
        pa = fminf(fmaxf(pa, -15.f), 15.f);
        float nn = fast_tanh_clamped(pa);
        float h = (1.f - z) * nn + z * hprev;
        hprev = h;
        ssum += h;
        ssq += h * h;
        if (LAYER == 2) { mx = fmaxf(mx, h); mn = fminf(mn, h); }
        __half yh = __float2half(h);
        if (kq < 2) {
            // write h_t for unit u into the other buffer (padded layout)
            ((__half*)hb4[(t + 1) & 1][u >> 6])[u & 63] = yh;
            if (LAYER == 1) yp[(size_t)t * 256 + u] = yh;   // stays in flight
        }
        lds_barrier();   // LDS-only drain: xw loads / y stores not drained
    }
    if (kq < 2) {
        atomicAdd(&stats[u], ssum);
        atomicAdd(&stats[256 + u], ssq);
        if (LAYER == 2) {
            mx_out[b * 256 + u] = mx;
            mn_out[b * 256 + u] = mn;
        }
    }
}

// Fold BN1 (training-mode batch stats) into layer-2 input weights.
__global__ void fold_bn1(const float* __restrict__ w_ih2, const float* __restrict__ b_ih2,
                         const float* __restrict__ g1, const float* __restrict__ be1,
                         const float* __restrict__ stats1,
                         __half* __restrict__ w_eff, float* __restrict__ b_eff) {
    const int g = blockIdx.x, lane = threadIdx.x;  // 768 blocks x 64 threads
    const float invN = 1.f / 65536.f;
    float partial = 0.f;
    for (int c = lane; c < 256; c += 64) {
        float mu = stats1[c] * invN;
        float var = stats1[256 + c] * invN - mu * mu;
        float s = g1[c] * rsqrtf(var + 1e-5f);
        float sh = be1[c] - mu * s;
        float w = w_ih2[g * 256 + c];
        w_eff[g * 256 + c] = __float2half(w * s);
        partial += w * sh;
    }
    #pragma unroll
    for (int off = 32; off > 0; off >>= 1) partial += __shfl_down(partial, off);
    if (lane == 0) b_eff[g] = b_ih2[g] + partial;
}

// BN2 affine -> time max-pool (max if scale>=0 else min) -> tanh -> FC
__global__ void final_kernel(const float* __restrict__ stats2,
                             const float* __restrict__ mx, const float* __restrict__ mn,
                             const float* __restrict__ g2, const float* __restrict__ be2,
                             const float* __restrict__ w_fc, const float* __restrict__ b_fc,
                             float* __restrict__ out) {
    __shared__ float v[256];
    const int b = blockIdx.x, c = threadIdx.x;
    const float invN = 1.f / 65536.f;
    float mu = stats2[c] * invN;
    float var = stats2[256 + c] * invN - mu * mu;
    float s = g2[c] * rsqrtf(var + 1e-5f);
    float d = be2[c] - mu * s;
    float M = (s >= 0.f) ? mx[b * 256 + c] : mn[b * 256 + c];
    v[c] = tanhf(s * M + d);
    __syncthreads();
    if (c < 128) {
        float acc = b_fc[c];
        for (int k = 0; k < 256; ++k) acc += v[k] * w_fc[c * 256 + k];
        out[b * 128 + c] = acc;
    }
}

extern "C" void kernel_launch(void* const* d_in, const int* in_sizes, int n_in,
                              void* d_out, int out_size, void* d_ws, size_t ws_size,
                              hipStream_t stream) {
    const float* x     = (const float*)d_in[0];
    const float* w_ih1 = (const float*)d_in[1];
    const float* w_hh1 = (const float*)d_in[2];
    const float* b_ih1 = (const float*)d_in[3];
    const float* b_hh1 = (const float*)d_in[4];
    const float* g1    = (const float*)d_in[5];
    const float* be1   = (const float*)d_in[6];
    const float* w_ih2 = (const float*)d_in[7];
    const float* w_hh2 = (const float*)d_in[8];
    const float* b_ih2 = (const float*)d_in[9];
    const float* b_hh2 = (const float*)d_in[10];
    const float* g2    = (const float*)d_in[11];
    const float* be2   = (const float*)d_in[12];
    const float* w_fc  = (const float*)d_in[13];
    const float* b_fc  = (const float*)d_in[14];
    float* out = (float*)d_out;

    char* ws = (char*)d_ws;
    size_t off = 0;
    __half*  xw   = (__half*)(ws + off);  off += (size_t)65536 * 768 * 2;  // shared by both layers
    __half*  y1   = (__half*)(ws + off);  off += (size_t)65536 * 256 * 2;
    __half2* wp1  = (__half2*)(ws + off); off += (size_t)768 * 128 * 4;
    __half2* wp2  = (__half2*)(ws + off); off += (size_t)768 * 128 * 4;
    __half*  weff = (__half*)(ws + off);  off += (size_t)768 * 256 * 2;
    float*   beff = (float*)(ws + off);   off += (size_t)768 * 4;
    float*   stats= (float*)(ws + off);   off += (size_t)1024 * 4;         // sum1,sq1,sum2,sq2
    float*   mx2  = (float*)(ws + off);   off += (size_t)64 * 256 * 4;
    float*   mn2  = (float*)(ws + off);   off += (size_t)64 * 256 * 4;

    (void)hipMemsetAsync(stats, 0, 4096, stream);

    pack_whh<<<dim3(768, 2), dim3(128), 0, stream>>>(w_hh1, w_hh2, wp1, wp2);
    gemm_xw1<<<dim3(12, 1024), dim3(256), 0, stream>>>(x, w_ih1, b_ih1, xw);
    rec_kernel<1><<<dim3(64), dim3(512), 0, stream>>>(wp1, b_hh1, xw, y1, stats,
                                                      (float*)nullptr, (float*)nullptr);
    fold_bn1<<<dim3(768), dim3(64), 0, stream>>>(w_ih2, b_ih2, g1, be1, stats, weff, beff);
    gemm_xw2<<<dim3(12, 1024), dim3(256), 0, stream>>>((const __half2*)y1, (const __half2*)weff,
                                                       beff, xw);
    rec_kernel<2><<<dim3(64), dim3(512), 0, stream>>>(wp2, b_hh2, xw, (__half*)nullptr,
                                                      stats + 512, mx2, mn2);
    final_kernel<<<dim3(64), dim3(256), 0, stream>>>(stats + 512, mx2, mn2, g2, be2,
                                                     w_fc, b_fc, out);
}